// Round 14
// baseline (450.656 us; speedup 1.0000x reference)
//
#include <hip/hip_runtime.h>
#include <hip/hip_bf16.h>
#include <hip/hip_fp16.h>

// GAT round 13: R12 + software-pipelined B-prefetch in attn32 (flatten j-loop
// to 128 j16 iters, prefetch next iter's 4 HB16 fragments into registers;
// ~230 VGPRs at 2 waves/SIMD budget of 256). Everything else identical to R12.

#define NN 4096
#define FF 512
#define HH 256
#define KK 8
#define KH 2048  // KK*HH

typedef __attribute__((ext_vector_type(8))) short bf16x8;
typedef __attribute__((ext_vector_type(4))) float f32x4;
typedef __attribute__((ext_vector_type(16))) float f32x16;
typedef _Float16 h16x2 __attribute__((ext_vector_type(2)));
typedef _Float16 h16x8 __attribute__((ext_vector_type(8)));

__device__ inline short f2bf(float x) {
    __hip_bfloat16 b = __float2bfloat16(x);
    return *reinterpret_cast<short*>(&b);
}
__device__ inline short to_bf(float x) { return f2bf(x); }
__device__ inline short to_bf(short x) { return x; }

__device__ inline unsigned int pkh(float a, float b) {
    auto r = __builtin_amdgcn_cvt_pkrtz(a, b);  // __fp16 ext_vector(2)
    unsigned int u;
    __builtin_memcpy(&u, &r, 4);
    return u;
}
__device__ inline unsigned int h2mul(unsigned int a, unsigned int b) {
    h16x2 av, bv;
    __builtin_memcpy(&av, &a, 4);
    __builtin_memcpy(&bv, &b, 4);
    h16x2 r = av * bv;
    unsigned int u;
    __builtin_memcpy(&u, &r, 4);
    return u;
}
__device__ inline unsigned int h2max(unsigned int a, unsigned int b) {
    h16x2 av, bv;
    __builtin_memcpy(&av, &a, 4);
    __builtin_memcpy(&bv, &b, 4);
    h16x2 r = __builtin_elementwise_max(av, bv);
    unsigned int u;
    __builtin_memcpy(&u, &r, 4);
    return u;
}
__device__ inline float h2dot1(unsigned int a, float c) {
    h16x2 av;
    __builtin_memcpy(&av, &a, 4);
    h16x2 one = {(_Float16)1.0f, (_Float16)1.0f};
    return __builtin_amdgcn_fdot2(av, one, c, false);
}

// monotone float<->uint encoding for atomicMax
__device__ inline unsigned int enc_f(float x) {
    unsigned int u = __float_as_uint(x);
    return (u & 0x80000000u) ? ~u : (u | 0x80000000u);
}
__device__ inline float dec_f(unsigned int e) {
    unsigned int u = (e & 0x80000000u) ? (e ^ 0x80000000u) : ~e;
    return __uint_as_float(u);
}

// ---- mask pack: adjacency fp32 -> bitmask (2 MB); only adjacency reader ----
__global__ void pack_mask_kernel(const float* __restrict__ adj,
                                 unsigned int* __restrict__ mbits) {
    int i = blockIdx.x;
    int lane = threadIdx.x & 63;
    int wv = threadIdx.x >> 6;
    for (int j0 = wv * 64; j0 < NN; j0 += 256) {
        float v = adj[(size_t)i * NN + j0 + lane];
        unsigned long long b = __ballot(v == 1.0f);
        if (lane == 0) {
            mbits[i * 128 + (j0 >> 5)]     = (unsigned int)(b & 0xffffffffull);
            mbits[i * 128 + (j0 >> 5) + 1] = (unsigned int)(b >> 32);
        }
    }
}

// ---- row-major [M][K] (fp32 or bf16 bits) -> A-frag bf16 (16x16x32 layout) ----
template <typename T>
__global__ __launch_bounds__(256) void cvt_a_frag_kernel(const T* __restrict__ src,
                                                         bf16x8* __restrict__ dst, int K) {
    int t = threadIdx.x, lane = t & 63, w = t >> 6, mt = blockIdx.x;
    int Kt = K >> 5;
    int m = mt * 16 + (lane & 15), kq = (lane >> 4) * 8;
    for (int kt = w; kt < Kt; kt += 4) {
        size_t base = (size_t)m * K + kt * 32 + kq;
        bf16x8 v;
#pragma unroll
        for (int jj = 0; jj < 8; jj++) v[jj] = to_bf(src[base + jj]);
        dst[((size_t)mt * Kt + kt) * 64 + lane] = v;
    }
}

// ---- W1 [HH][FF] and W2 [HH][KH] (B^T) fp32 -> B-frag bf16, one launch ----
__global__ __launch_bounds__(256) void cvt_bt2_kernel(const float* __restrict__ W1,
                                                      const float* __restrict__ W2,
                                                      bf16x8* __restrict__ d1,
                                                      bf16x8* __restrict__ d2) {
    const float* Wm = blockIdx.y ? W2 : W1;
    bf16x8* dst = blockIdx.y ? d2 : d1;
    int K = blockIdx.y ? KH : FF;
    constexpr int Nt = HH / 16;
    int t = threadIdx.x, lane = t & 63, w = t >> 6, nt = blockIdx.x;
    int Kt = K >> 5;
    int n = nt * 16 + (lane & 15), kq = (lane >> 4) * 8;
    for (int kt = w; kt < Kt; kt += 4) {
        size_t base = (size_t)n * K + kt * 32 + kq;
        bf16x8 v;
#pragma unroll
        for (int jj = 0; jj < 8; jj++) v[jj] = f2bf(Wm[base + jj]);
        dst[((size_t)kt * Nt + nt) * 64 + lane] = v;
    }
}

// ---- src [K][W] fp32 -> B-frag bf16 (16x16x32 layout, LDS-staged) ----
template <int W>
__global__ __launch_bounds__(256) void cvt_b_frag_kernel(const float* __restrict__ src,
                                                         bf16x8* __restrict__ dst) {
    __shared__ float hs[32][W + 8];
    constexpr int Nt = W / 16;
    int t = threadIdx.x, jb = blockIdx.x;
    {
        int r = t >> 3, cb = (t & 7) * (W / 8);
        const float* sp = &src[(size_t)(jb * 32 + r) * W + cb];
#pragma unroll
        for (int q = 0; q < W / 32; q++) *(float4*)&hs[r][cb + q * 4] = *(const float4*)&sp[q * 4];
    }
    __syncthreads();
    for (int id = t; id < Nt * 64; id += 256) {
        int nt = id >> 6, lane = id & 63;
        int c = nt * 16 + (lane & 15), q8 = (lane >> 4) * 8;
        bf16x8 v;
#pragma unroll
        for (int jj = 0; jj < 8; jj++) v[jj] = f2bf(hs[q8 + jj][c]);
        dst[((size_t)jb * Nt + nt) * 64 + lane] = v;
    }
}

// ---- fragment-direct bf16 MFMA GEMM, 64x64 tile: C = A@B (+bias) ----
__global__ __launch_bounds__(256) void gemm_frag_kernel(
    const bf16x8* __restrict__ Af, const bf16x8* __restrict__ Bf,
    const float* __restrict__ bias, float* __restrict__ C,
    int Kt, int Nt, int Nrow) {
    int t = threadIdx.x, lane = t & 63, w = t >> 6;
    int quad = lane >> 4, c16 = lane & 15;
    int wm = w & 1, wn = w >> 1;
    int mt0 = blockIdx.y * 4 + wm * 2;
    int nt0 = blockIdx.x * 4 + wn * 2;
    f32x4 acc[2][2];
#pragma unroll
    for (int i = 0; i < 2; i++)
#pragma unroll
        for (int j = 0; j < 2; j++) acc[i][j] = (f32x4){0.f, 0.f, 0.f, 0.f};
    const bf16x8* ap = Af + (size_t)mt0 * Kt * 64 + lane;
    const bf16x8* bp = Bf + (size_t)nt0 * 64 + lane;
#pragma unroll 4
    for (int kt = 0; kt < Kt; kt++) {
        bf16x8 a0 = ap[(size_t)kt * 64];
        bf16x8 a1 = ap[((size_t)Kt + kt) * 64];
        bf16x8 b0 = bp[(size_t)kt * Nt * 64];
        bf16x8 b1 = bp[((size_t)kt * Nt + 1) * 64];
        acc[0][0] = __builtin_amdgcn_mfma_f32_16x16x32_bf16(a0, b0, acc[0][0], 0, 0, 0);
        acc[0][1] = __builtin_amdgcn_mfma_f32_16x16x32_bf16(a0, b1, acc[0][1], 0, 0, 0);
        acc[1][0] = __builtin_amdgcn_mfma_f32_16x16x32_bf16(a1, b0, acc[1][0], 0, 0, 0);
        acc[1][1] = __builtin_amdgcn_mfma_f32_16x16x32_bf16(a1, b1, acc[1][1], 0, 0, 0);
    }
#pragma unroll
    for (int i = 0; i < 2; i++) {
#pragma unroll
        for (int j = 0; j < 2; j++) {
            int n = (nt0 + j) * 16 + c16;
            float bv = bias ? bias[n] : 0.f;
#pragma unroll
            for (int reg = 0; reg < 4; reg++) {
                int m = (mt0 + i) * 16 + quad * 4 + reg;
                C[(size_t)m * Nrow + n] = acc[i][j][reg] + bv;
            }
        }
    }
}

// ---- gemm1: C = adj @ B, A from mbits in-register; 32x128 tile ----
__global__ __launch_bounds__(256) void gemm_adj_kernel(
    const unsigned int* __restrict__ mbits, const bf16x8* __restrict__ Bf,
    float* __restrict__ C, int Kt, int Nt, int Nrow) {
    int t = threadIdx.x, lane = t & 63, w = t >> 6;
    int quad = lane >> 4, c16 = lane & 15;
    int wm = w & 1, wn = w >> 1;
    int mt = blockIdx.y * 2 + wm;
    int nt0 = blockIdx.x * 8 + wn * 4;
    int row = mt * 16 + (lane & 15), q8 = (lane >> 4) * 8;
    f32x4 acc[4];
#pragma unroll
    for (int j = 0; j < 4; j++) acc[j] = (f32x4){0.f, 0.f, 0.f, 0.f};
    const bf16x8* bp = Bf + (size_t)nt0 * 64 + lane;
#pragma unroll 2
    for (int kt = 0; kt < Kt; kt++) {
        unsigned int w0 = mbits[(size_t)row * 128 + kt];
        unsigned int mb0 = (w0 >> q8) & 0xffu;
        union { unsigned int u[4]; bf16x8 v; } A0;
#pragma unroll
        for (int jp = 0; jp < 4; jp++) {
            unsigned int u0 = (mb0 >> (2 * jp)) & 3u;
            A0.u[jp] = ((u0 * 0x8001u) & 0x10001u) * 0x3F80u;  // bf16 1.0 pair
        }
        bf16x8 b0 = bp[(size_t)kt * Nt * 64];
        bf16x8 b1 = bp[((size_t)kt * Nt + 1) * 64];
        bf16x8 b2 = bp[((size_t)kt * Nt + 2) * 64];
        bf16x8 b3 = bp[((size_t)kt * Nt + 3) * 64];
        acc[0] = __builtin_amdgcn_mfma_f32_16x16x32_bf16(A0.v, b0, acc[0], 0, 0, 0);
        acc[1] = __builtin_amdgcn_mfma_f32_16x16x32_bf16(A0.v, b1, acc[1], 0, 0, 0);
        acc[2] = __builtin_amdgcn_mfma_f32_16x16x32_bf16(A0.v, b2, acc[2], 0, 0, 0);
        acc[3] = __builtin_amdgcn_mfma_f32_16x16x32_bf16(A0.v, b3, acc[3], 0, 0, 0);
    }
#pragma unroll
    for (int j = 0; j < 4; j++) {
        int n = (nt0 + j) * 16 + c16;
#pragma unroll
        for (int reg = 0; reg < 4; reg++) {
            int mm = mt * 16 + quad * 4 + reg;
            C[(size_t)mm * Nrow + n] = acc[j][reg];
        }
    }
}

// ---- prep: h -> HB16 (32x32x16 f16 B-frag) + srcT/dstT (log2e) + maxdst ----
__global__ __launch_bounds__(256) void prep_kernel(const float* __restrict__ h,
                                                   const float* __restrict__ aw,
                                                   const float* __restrict__ ab,
                                                   h16x8* __restrict__ HB16,
                                                   float* __restrict__ srcT,
                                                   float* __restrict__ dstT,
                                                   unsigned int* __restrict__ maxd_u) {
    __shared__ __align__(16) float hs[32][264];
    __shared__ __align__(16) float awl[KK * 512];
    int t = threadIdx.x, jb = blockIdx.x;
#pragma unroll
    for (int q = 0; q < 4; q++)
        *(float4*)&awl[(t + q * 256) * 4] = *(const float4*)&aw[(t + q * 256) * 4];
    {
        int r = t >> 3, cb = (t & 7) * 32;
        const float* hp = &h[(size_t)(jb * 32 + r) * HH + cb];
#pragma unroll
        for (int q = 0; q < 8; q++) *(float4*)&hs[r][cb + q * 4] = *(const float4*)&hp[q * 4];
    }
    __syncthreads();
#pragma unroll
    for (int it = 0; it < 4; it++) {
        int id = t + it * 256;
        int q = id >> 9, nt = (id >> 6) & 7, lane = id & 63;
        int c = nt * 32 + (lane & 31), j8 = q * 16 + (lane >> 5) * 8;
        union { unsigned int u[4]; h16x8 v; } pk;
#pragma unroll
        for (int jp = 0; jp < 4; jp++)
            pk.u[jp] = pkh(hs[j8 + 2 * jp][c], hs[j8 + 2 * jp + 1][c]);
        HB16[((size_t)(jb * 2 + q)) * 512 + nt * 64 + lane] = pk.v;
    }
    {
        const float LOG2E = 1.4426950408889634f;
        int row = t & 31, head = t >> 5;
        float s = ab[head], d = 0.f;
        const float* ws = &awl[head * 512];
        const float* wd = ws + 256;
#pragma unroll 4
        for (int c = 0; c < 256; c += 4) {
            float4 hv = *(const float4*)&hs[row][c];
            float4 a4 = *(const float4*)&ws[c];
            float4 b4 = *(const float4*)&wd[c];
            s += hv.x * a4.x + hv.y * a4.y + hv.z * a4.z + hv.w * a4.w;
            d += hv.x * b4.x + hv.y * b4.y + hv.z * b4.z + hv.w * b4.w;
        }
        float ds = d * LOG2E;
        srcT[head * NN + jb * 32 + row] = s * LOG2E;
        dstT[head * NN + jb * 32 + row] = ds;
        float mx = ds;
#pragma unroll
        for (int off = 16; off > 0; off >>= 1) mx = fmaxf(mx, __shfl_xor(mx, off));
        if (row == 0) atomicMax(&maxd_u[head], enc_f(mx));
    }
}

// ---- attention (R8 shape): 32 rows x 2 heads, 4 waves = jh2 x ch2 ----------
// Flattened 128-iter j16 loop with 1-deep register prefetch of the 4 HB16
// B-fragments (hides ~200cyc L2 latency behind P-gen of prior iteration).
template <int MODE>
__global__ __launch_bounds__(256, 2) void attn32_kernel(
    const float* __restrict__ h, const float* __restrict__ srcT,
    const float* __restrict__ dstT, const unsigned int* __restrict__ maxd_u,
    const unsigned int* __restrict__ mbits, const h16x8* __restrict__ HB16,
    void* __restrict__ outp) {
    __shared__ __align__(16) char smraw[49600];
    __shared__ float l_all[2][2][32];
    __shared__ float linv_l[2][32];
    unsigned short* e1t = (unsigned short*)smraw;            // [2][4096] f16 (loop)
    unsigned short* e2t = (unsigned short*)(smraw + 16384);  // [2][4096] f16 (loop)
    unsigned int* mrow = (unsigned int*)(smraw + 32768);     // [32*131]      (loop)
    float* accbuf = (float*)smraw;                           // 32 KB         (epi)

    int t = threadIdx.x;
    int i0 = blockIdx.x * 32;
    int k0 = blockIdx.y * 2;

    float Dv0 = dec_f(maxd_u[k0]), Dv1 = dec_f(maxd_u[k0 + 1]);
#pragma unroll
    for (int q = 0; q < 8; q++) {
        int idx = t + q * 256;                // 0..2047, 4 entries each
        int hh = idx >> 10, off = (idx & 1023) * 4;
        float D = hh ? Dv1 : Dv0;
        float4 dv = *(const float4*)&dstT[(size_t)(k0 + hh) * NN + off];
        float d0 = dv.x - D, d1 = dv.y - D, d2 = dv.z - D, d3 = dv.w - D;
        uint2 p1, p2;
        p1.x = pkh(__builtin_amdgcn_exp2f(d0), __builtin_amdgcn_exp2f(d1));
        p1.y = pkh(__builtin_amdgcn_exp2f(d2), __builtin_amdgcn_exp2f(d3));
        p2.x = pkh(__builtin_amdgcn_exp2f(0.01f * d0), __builtin_amdgcn_exp2f(0.01f * d1));
        p2.y = pkh(__builtin_amdgcn_exp2f(0.01f * d2), __builtin_amdgcn_exp2f(0.01f * d3));
        *(uint2*)&e1t[hh * 4096 + off] = p1;
        *(uint2*)&e2t[hh * 4096 + off] = p2;
    }
#pragma unroll
    for (int q = 0; q < 16; q++) {
        int idx = t + q * 256;                // 0..4095
        int r = idx >> 7, wd = idx & 127;
        mrow[r * 131 + wd] = mbits[(size_t)(i0 + r) * 128 + wd];
    }
    __syncthreads();

    int lane = t & 63, w = t >> 6;
    int jh = w & 1, ch = w >> 1;
    int rowl = lane & 31, jsub = (lane >> 5) * 8;

    unsigned int AcPk[2], BcPk[2];
    float lacc[2] = {0.f, 0.f};
#pragma unroll
    for (int hh = 0; hh < 2; hh++) {
        float sL = srcT[(size_t)(k0 + hh) * NN + i0 + rowl];
        float xm = sL + (hh ? Dv1 : Dv0);
        float mL = fmaxf(xm, 0.01f * xm);
        float Acf = __builtin_amdgcn_exp2f(xm - mL);
        float Bcf = __builtin_amdgcn_exp2f(fmaf(0.01f, xm, -mL));
        AcPk[hh] = pkh(Acf, Acf);
        BcPk[hh] = pkh(Bcf, Bcf);
    }

    f32x16 acc[2][4];
#pragma unroll
    for (int hh = 0; hh < 2; hh++)
#pragma unroll
        for (int nt = 0; nt < 4; nt++)
#pragma unroll
            for (int r = 0; r < 16; r++) acc[hh][nt][r] = 0.f;

    const unsigned short* e1b0 = e1t;
    const unsigned short* e1b1 = e1t + 4096;
    const unsigned short* e2b0 = e2t;
    const unsigned short* e2b1 = e2t + 4096;

    int jbase = jh * 128;  // this wave's j16 range: [jbase, jbase+128)
    const h16x8* bpbase = HB16 + (size_t)(ch * 4) * 64 + lane;
    h16x8 bv0, bv1, bv2, bv3;
    {
        const h16x8* bp = bpbase + (size_t)jbase * 512;
        bv0 = bp[0]; bv1 = bp[64]; bv2 = bp[128]; bv3 = bp[192];
    }

#pragma unroll 2
    for (int it = 0; it < 128; it++) {
        int j16 = jbase + it;
        // prefetch next iteration's B fragments (last iter reads 4KB past the
        // 2MB HB16 region — still inside d_ws, values unused)
        h16x8 nb0, nb1, nb2, nb3;
        {
            const h16x8* bp = bpbase + (size_t)(j16 + 1) * 512;
            nb0 = bp[0]; nb1 = bp[64]; nb2 = bp[128]; nb3 = bp[192];
        }
        unsigned int word = mrow[rowl * 131 + (j16 >> 1)];
        unsigned int mb = (word >> ((j16 & 1) * 16 + jsub)) & 0xffu;
        unsigned int mw[4];
#pragma unroll
        for (int jp = 0; jp < 4; jp++) {
            unsigned int u2 = (mb >> (2 * jp)) & 3u;
            mw[jp] = ((u2 * 0x8001u) & 0x10001u) * 0xffffu;
        }
        int eoff = j16 * 16 + jsub;
        union { unsigned int u[4]; h16x8 v; } P0;
        {
            uint4 E1 = *(const uint4*)&e1b0[eoff];
            uint4 E2 = *(const uint4*)&e2b0[eoff];
            unsigned int v0 = h2max(h2mul(E1.x, AcPk[0]), h2mul(E2.x, BcPk[0])) & mw[0];
            unsigned int v1 = h2max(h2mul(E1.y, AcPk[0]), h2mul(E2.y, BcPk[0])) & mw[1];
            unsigned int v2 = h2max(h2mul(E1.z, AcPk[0]), h2mul(E2.z, BcPk[0])) & mw[2];
            unsigned int v3 = h2max(h2mul(E1.w, AcPk[0]), h2mul(E2.w, BcPk[0])) & mw[3];
            lacc[0] = h2dot1(v0, lacc[0]);
            lacc[0] = h2dot1(v1, lacc[0]);
            lacc[0] = h2dot1(v2, lacc[0]);
            lacc[0] = h2dot1(v3, lacc[0]);
            P0.u[0] = v0; P0.u[1] = v1; P0.u[2] = v2; P0.u[3] = v3;
        }
        acc[0][0] = __builtin_amdgcn_mfma_f32_32x32x16_f16(P0.v, bv0, acc[0][0], 0, 0, 0);
        acc[0][1] = __builtin_amdgcn_mfma_f32_32x32x16_f16(P0.v, bv1, acc[0][1], 0, 0, 0);
        acc[0][2] = __builtin_amdgcn_mfma_f32_32x32x16_f16(P0.v, bv2, acc[0][2], 0, 0, 0);
        acc[0][3] = __builtin_amdgcn_mfma_f32_32x32x16_f16(P0.v, bv3, acc[0][3], 0, 0, 0);
        union { unsigned int u[4]; h16x8 v; } P1;
        {
            uint4 E1 = *(const uint4*)&e1b1[eoff];
            uint4 E2 = *(const uint4*)&e2b1[eoff];
            unsigned int v0 = h2max(h2mul(E1.x, AcPk[1]), h2mul(E2.x, BcPk[1])) & mw[0];
            unsigned int v1 = h2max(h2mul(E1.y, AcPk[1]), h2mul(E2.y, BcPk[1])) & mw[1];
            unsigned int v2 = h2max(h2mul(E1.z, AcPk[1]), h2mul(E2.z, BcPk[1])) & mw[2];
            unsigned int v3 = h2max(h2mul(E1.w, AcPk[1]), h2mul(E2.w, BcPk[1])) & mw[3];
            lacc[1] = h2dot1(v0, lacc[1]);
            lacc[1] = h2dot1(v1, lacc[1]);
            lacc[1] = h2dot1(v2, lacc[1]);
            lacc[1] = h2dot1(v3, lacc[1]);
            P1.u[0] = v0; P1.u[1] = v1; P1.u[2] = v2; P1.u[3] = v3;
        }
        acc[1][0] = __builtin_amdgcn_mfma_f32_32x32x16_f16(P1.v, bv0, acc[1][0], 0, 0, 0);
        acc[1][1] = __builtin_amdgcn_mfma_f32_32x32x16_f16(P1.v, bv1, acc[1][1], 0, 0, 0);
        acc[1][2] = __builtin_amdgcn_mfma_f32_32x32x16_f16(P1.v, bv2, acc[1][2], 0, 0, 0);
        acc[1][3] = __builtin_amdgcn_mfma_f32_32x32x16_f16(P1.v, bv3, acc[1][3], 0, 0, 0);
        bv0 = nb0; bv1 = nb1; bv2 = nb2; bv3 = nb3;
    }

    lacc[0] += __shfl_xor(lacc[0], 32);
    lacc[1] += __shfl_xor(lacc[1], 32);
    if (ch == 0 && lane < 32) {
        l_all[jh][0][lane] = lacc[0];
        l_all[jh][1][lane] = lacc[1];
    }
    __syncthreads();  // l_all visible; loop-phase LDS dead
    if (t < 32) {
#pragma unroll
        for (int hh = 0; hh < 2; hh++) {
            float lt = l_all[0][hh][t] + l_all[1][hh][t];
            linv_l[hh][t] = (lt > 0.f) ? 1.f / lt : 0.f;  // isolated row -> 0
        }
    }
    __syncthreads();

#pragma unroll
    for (int r = 0; r < 2; r++) {
        if (jh == 1) {
#pragma unroll
            for (int nt = 0; nt < 4; nt++) {
                float* dp = accbuf + (size_t)((ch * 4 + nt) * 16) * 64 + lane;
#pragma unroll
                for (int reg = 0; reg < 16; reg++) dp[reg * 64] = acc[r][nt][reg];
            }
        }
        __syncthreads();
        if (jh == 0) {
            int khead = k0 + r;
#pragma unroll
            for (int nt = 0; nt < 4; nt++) {
                const float* sp = accbuf + (size_t)((ch * 4 + nt) * 16) * 64 + lane;
                int c = (ch * 4 + nt) * 32 + (lane & 31);
#pragma unroll
                for (int reg = 0; reg < 16; reg++) {
                    int rowloc = (reg & 3) + 8 * (reg >> 2) + 4 * (lane >> 5);
                    float v = (acc[r][nt][reg] + sp[reg * 64]) * linv_l[r][rowloc];
                    int i = i0 + rowloc;
                    if (MODE == 1) {
                        v += h[(size_t)i * HH + c];
                        v = (v > 0.f) ? v : (__expf(v) - 1.f);  // elu
                        ((short*)outp)[(size_t)i * KH + (size_t)khead * HH + c] = f2bf(v);
                    } else {
                        ((short*)outp)[(size_t)khead * NN * HH + (size_t)i * HH + c] = f2bf(v);
                    }
                }
            }
        }
        if (r == 0) __syncthreads();
    }
}

// ---------------- elu(avg of heads) column partial sums (bf16 planes) --------
__global__ void colsum_kernel(const float* __restrict__ h2,
                              const short* __restrict__ heads,
                              float* __restrict__ partial) {
    int c = threadIdx.x;
    int b = blockIdx.x;
    float s = 0.f;
    for (int il = 0; il < 16; il++) {
        int i = b * 16 + il;
        float v = h2[(size_t)i * HH + c];
#pragma unroll
        for (int k = 0; k < KK; k++) {
            unsigned int bits = (unsigned int)(unsigned short)heads[(size_t)k * NN * HH + (size_t)i * HH + c];
            v += 0.125f * __uint_as_float(bits << 16);
        }
        s += (v > 0.f) ? v : (__expf(v) - 1.f);
    }
    partial[b * HH + c] = s;
}

__global__ void final_kernel(const float* __restrict__ partial,
                             const float* __restrict__ out_w,
                             const float* __restrict__ out_b,
                             float* __restrict__ dout) {
    __shared__ float red[256];
    int c = threadIdx.x;
    float s = 0.f;
    for (int b = 0; b < 256; b++) s += partial[b * HH + c];
    red[c] = (s / 4096.f) * out_w[c];
    __syncthreads();
    for (int off = 128; off > 0; off >>= 1) {
        if (c < off) red[c] += red[c + off];
        __syncthreads();
    }
    if (c == 0) dout[0] = red[0] + out_b[0];
}

extern "C" void kernel_launch(void* const* d_in, const int* in_sizes, int n_in,
                              void* d_out, int out_size, void* d_ws, size_t ws_size,
                              hipStream_t stream) {
    (void)in_sizes; (void)n_in; (void)out_size; (void)ws_size;
    const float* adj   = (const float*)d_in[0];
    const float* feats = (const float*)d_in[1];
    const float* W1_w  = (const float*)d_in[2];
    const float* W1_b  = (const float*)d_in[3];
    const float* a1_w  = (const float*)d_in[4];
    const float* a1_b  = (const float*)d_in[5];
    const float* W2_w  = (const float*)d_in[6];
    const float* W2_b  = (const float*)d_in[7];
    const float* a2_w  = (const float*)d_in[8];
    const float* a2_b  = (const float*)d_in[9];
    const float* out_w = (const float*)d_in[10];
    const float* out_b = (const float*)d_in[11];

    char* w = (char*)d_ws;
    const size_t MB = 1ull << 20;
    const size_t KB = 1ull << 10;
    // Disjoint-lifetime map (total 46 MB):
    unsigned int* mbits = (unsigned int*)(w);              // 0..2MB    (whole run)
    bf16x8* Bfeats = (bf16x8*)(w + 2 * MB);                // 2..6MB    (ph1)
    float*  tmp1   = (float*)(w + 6 * MB);                 // 6..14MB   (ph1)
    bf16x8* tmp1a  = (bf16x8*)(w + 14 * MB);               // 14..18MB  (ph1)
    short*  h1nb   = (short*)(w + 2 * MB);                 // 2..18MB   (ph2, ph1 scratch dead)
    short*  planes = (short*)(w + 2 * MB);                 // 2..18MB   (ph3)
    bf16x8* h1na   = (bf16x8*)(w + 18 * MB);               // 18..34MB  (ph2)
    float*  h2     = (float*)(w + 34 * MB);                // 34..38MB  (ph2->3)
    float*  h1     = (float*)(w + 38 * MB);                // 38..42MB  (ph1->2)
    h16x8*  HB16   = (h16x8*)(w + 42 * MB);                // 42..44MB  (ph2, ph3)
    bf16x8* W1f    = (bf16x8*)(w + 44 * MB);               // 44..44.25MB (ph1)
    bf16x8* W2f    = (bf16x8*)(w + 44 * MB + 256 * KB);    // 44.25..45.25MB (ph1->2)
    float*  srcT   = (float*)(w + 45 * MB + 256 * KB);     // 128 KB
    float*  dstT   = (float*)(w + 45 * MB + 384 * KB);     // 128 KB
    unsigned int* maxd_u = (unsigned int*)(w + 45 * MB + 512 * KB);  // 32 B
    float*  partial = (float*)(w + 45 * MB + 768 * KB);    // 256 KB -> ends 46MB

    // --- phase 1: h1 = (A @ feats) @ W1^T + b1 ---
    pack_mask_kernel<<<NN, 256, 0, stream>>>(adj, mbits);
    cvt_b_frag_kernel<FF><<<NN / 32, 256, 0, stream>>>(feats, Bfeats);
    cvt_bt2_kernel<<<dim3(HH / 16, 2), 256, 0, stream>>>(W1_w, W2_w, W1f, W2f);
    gemm_adj_kernel<<<dim3(FF / 128, NN / 32), 256, 0, stream>>>(
        mbits, Bfeats, tmp1, NN / 32, FF / 16, FF);
    cvt_a_frag_kernel<float><<<NN / 16, 256, 0, stream>>>(tmp1, tmp1a, FF);
    gemm_frag_kernel<<<dim3(HH / 64, NN / 64), 256, 0, stream>>>(
        tmp1a, W1f, W1_b, h1, FF / 32, HH / 16, HH);

    // --- phase 2: layer-1 attention -> h1nb (bf16), then h2 ---
    (void)hipMemsetAsync(maxd_u, 0, KK * sizeof(unsigned int), stream);
    prep_kernel<<<NN / 32, 256, 0, stream>>>(h1, a1_w, a1_b, HB16, srcT, dstT, maxd_u);
    attn32_kernel<1><<<dim3(NN / 32, KK / 2), 256, 0, stream>>>(
        h1, srcT, dstT, maxd_u, mbits, HB16, h1nb);
    cvt_a_frag_kernel<short><<<NN / 16, 256, 0, stream>>>(h1nb, h1na, KH);
    gemm_frag_kernel<<<dim3(HH / 64, NN / 64), 256, 0, stream>>>(
        h1na, W2f, W2_b, h2, KH / 32, HH / 16, HH);

    // --- phase 3: layer-2 attention -> bf16 head planes, reduce ---
    (void)hipMemsetAsync(maxd_u, 0, KK * sizeof(unsigned int), stream);
    prep_kernel<<<NN / 32, 256, 0, stream>>>(h2, a2_w, a2_b, HB16, srcT, dstT, maxd_u);
    attn32_kernel<2><<<dim3(NN / 32, KK / 2), 256, 0, stream>>>(
        h2, srcT, dstT, maxd_u, mbits, HB16, planes);
    colsum_kernel<<<256, 256, 0, stream>>>(h2, planes, partial);
    final_kernel<<<1, 256, 0, stream>>>(partial, out_w, out_b, (float*)d_out);
}

// Round 15
// 424.802 us; speedup vs baseline: 1.0609x; 1.0609x over previous
//
#include <hip/hip_runtime.h>
#include <hip/hip_bf16.h>
#include <hip/hip_fp16.h>

// GAT round 14: tail fusion. gemm_adj + attn<1> write MFMA A-fragments directly
// (LDS transpose epilogues) -> cvt_a_frag kernels deleted; maxd init folded into
// pack_mask -> memsets deleted. 19 -> 12 dispatches. attn K-loop frozen (R13).

#define NN 4096
#define FF 512
#define HH 256
#define KK 8
#define KH 2048  // KK*HH

typedef __attribute__((ext_vector_type(8))) short bf16x8;
typedef __attribute__((ext_vector_type(4))) float f32x4;
typedef __attribute__((ext_vector_type(16))) float f32x16;
typedef _Float16 h16x2 __attribute__((ext_vector_type(2)));
typedef _Float16 h16x8 __attribute__((ext_vector_type(8)));

__device__ inline short f2bf(float x) {
    __hip_bfloat16 b = __float2bfloat16(x);
    return *reinterpret_cast<short*>(&b);
}

__device__ inline unsigned int pkh(float a, float b) {
    auto r = __builtin_amdgcn_cvt_pkrtz(a, b);  // __fp16 ext_vector(2)
    unsigned int u;
    __builtin_memcpy(&u, &r, 4);
    return u;
}
__device__ inline unsigned int h2mul(unsigned int a, unsigned int b) {
    h16x2 av, bv;
    __builtin_memcpy(&av, &a, 4);
    __builtin_memcpy(&bv, &b, 4);
    h16x2 r = av * bv;
    unsigned int u;
    __builtin_memcpy(&u, &r, 4);
    return u;
}
__device__ inline unsigned int h2max(unsigned int a, unsigned int b) {
    h16x2 av, bv;
    __builtin_memcpy(&av, &a, 4);
    __builtin_memcpy(&bv, &b, 4);
    h16x2 r = __builtin_elementwise_max(av, bv);
    unsigned int u;
    __builtin_memcpy(&u, &r, 4);
    return u;
}
__device__ inline float h2dot1(unsigned int a, float c) {
    h16x2 av;
    __builtin_memcpy(&av, &a, 4);
    h16x2 one = {(_Float16)1.0f, (_Float16)1.0f};
    return __builtin_amdgcn_fdot2(av, one, c, false);
}

// monotone float<->uint encoding for atomicMax
__device__ inline unsigned int enc_f(float x) {
    unsigned int u = __float_as_uint(x);
    return (u & 0x80000000u) ? ~u : (u | 0x80000000u);
}
__device__ inline float dec_f(unsigned int e) {
    unsigned int u = (e & 0x80000000u) ? (e ^ 0x80000000u) : ~e;
    return __uint_as_float(u);
}

// ---- mask pack: adjacency fp32 -> bitmask; also zero-inits 16 maxd slots ----
__global__ void pack_mask_kernel(const float* __restrict__ adj,
                                 unsigned int* __restrict__ mbits,
                                 unsigned int* __restrict__ maxd_u) {
    int i = blockIdx.x;
    if (i == 0 && threadIdx.x < 16) maxd_u[threadIdx.x] = 0;
    int lane = threadIdx.x & 63;
    int wv = threadIdx.x >> 6;
    for (int j0 = wv * 64; j0 < NN; j0 += 256) {
        float v = adj[(size_t)i * NN + j0 + lane];
        unsigned long long b = __ballot(v == 1.0f);
        if (lane == 0) {
            mbits[i * 128 + (j0 >> 5)]     = (unsigned int)(b & 0xffffffffull);
            mbits[i * 128 + (j0 >> 5) + 1] = (unsigned int)(b >> 32);
        }
    }
}

// ---- W1 [HH][FF] and W2 [HH][KH] (B^T) fp32 -> B-frag bf16, one launch ----
__global__ __launch_bounds__(256) void cvt_bt2_kernel(const float* __restrict__ W1,
                                                      const float* __restrict__ W2,
                                                      bf16x8* __restrict__ d1,
                                                      bf16x8* __restrict__ d2) {
    const float* Wm = blockIdx.y ? W2 : W1;
    bf16x8* dst = blockIdx.y ? d2 : d1;
    int K = blockIdx.y ? KH : FF;
    constexpr int Nt = HH / 16;
    int t = threadIdx.x, lane = t & 63, w = t >> 6, nt = blockIdx.x;
    int Kt = K >> 5;
    int n = nt * 16 + (lane & 15), kq = (lane >> 4) * 8;
    for (int kt = w; kt < Kt; kt += 4) {
        size_t base = (size_t)n * K + kt * 32 + kq;
        bf16x8 v;
#pragma unroll
        for (int jj = 0; jj < 8; jj++) v[jj] = f2bf(Wm[base + jj]);
        dst[((size_t)kt * Nt + nt) * 64 + lane] = v;
    }
}

// ---- src [K][W] fp32 -> B-frag bf16 (16x16x32 layout, LDS-staged) ----
template <int W>
__global__ __launch_bounds__(256) void cvt_b_frag_kernel(const float* __restrict__ src,
                                                         bf16x8* __restrict__ dst) {
    __shared__ float hs[32][W + 8];
    constexpr int Nt = W / 16;
    int t = threadIdx.x, jb = blockIdx.x;
    {
        int r = t >> 3, cb = (t & 7) * (W / 8);
        const float* sp = &src[(size_t)(jb * 32 + r) * W + cb];
#pragma unroll
        for (int q = 0; q < W / 32; q++) *(float4*)&hs[r][cb + q * 4] = *(const float4*)&sp[q * 4];
    }
    __syncthreads();
    for (int id = t; id < Nt * 64; id += 256) {
        int nt = id >> 6, lane = id & 63;
        int c = nt * 16 + (lane & 15), q8 = (lane >> 4) * 8;
        bf16x8 v;
#pragma unroll
        for (int jj = 0; jj < 8; jj++) v[jj] = f2bf(hs[q8 + jj][c]);
        dst[((size_t)jb * Nt + nt) * 64 + lane] = v;
    }
}

// ---- fragment-direct bf16 MFMA GEMM, 64x64 tile: C = A@B (+bias) ----
__global__ __launch_bounds__(256) void gemm_frag_kernel(
    const bf16x8* __restrict__ Af, const bf16x8* __restrict__ Bf,
    const float* __restrict__ bias, float* __restrict__ C,
    int Kt, int Nt, int Nrow) {
    int t = threadIdx.x, lane = t & 63, w = t >> 6;
    int quad = lane >> 4, c16 = lane & 15;
    int wm = w & 1, wn = w >> 1;
    int mt0 = blockIdx.y * 4 + wm * 2;
    int nt0 = blockIdx.x * 4 + wn * 2;
    f32x4 acc[2][2];
#pragma unroll
    for (int i = 0; i < 2; i++)
#pragma unroll
        for (int j = 0; j < 2; j++) acc[i][j] = (f32x4){0.f, 0.f, 0.f, 0.f};
    const bf16x8* ap = Af + (size_t)mt0 * Kt * 64 + lane;
    const bf16x8* bp = Bf + (size_t)nt0 * 64 + lane;
#pragma unroll 4
    for (int kt = 0; kt < Kt; kt++) {
        bf16x8 a0 = ap[(size_t)kt * 64];
        bf16x8 a1 = ap[((size_t)Kt + kt) * 64];
        bf16x8 b0 = bp[(size_t)kt * Nt * 64];
        bf16x8 b1 = bp[((size_t)kt * Nt + 1) * 64];
        acc[0][0] = __builtin_amdgcn_mfma_f32_16x16x32_bf16(a0, b0, acc[0][0], 0, 0, 0);
        acc[0][1] = __builtin_amdgcn_mfma_f32_16x16x32_bf16(a0, b1, acc[0][1], 0, 0, 0);
        acc[1][0] = __builtin_amdgcn_mfma_f32_16x16x32_bf16(a1, b0, acc[1][0], 0, 0, 0);
        acc[1][1] = __builtin_amdgcn_mfma_f32_16x16x32_bf16(a1, b1, acc[1][1], 0, 0, 0);
    }
#pragma unroll
    for (int i = 0; i < 2; i++) {
#pragma unroll
        for (int j = 0; j < 2; j++) {
            int n = (nt0 + j) * 16 + c16;
            float bv = bias ? bias[n] : 0.f;
#pragma unroll
            for (int reg = 0; reg < 4; reg++) {
                int m = (mt0 + i) * 16 + quad * 4 + reg;
                C[(size_t)m * Nrow + n] = acc[i][j][reg] + bv;
            }
        }
    }
}

// ---- gemm1: C = adj @ B from mbits; 32x128 tile; writes A-frag bf16 DIRECTLY ----
// out Afrag layout: [mt][kt(=16)][lane][8], mt = row/16, kt = col/32.
__global__ __launch_bounds__(256) void gemm_adj_kernel(
    const unsigned int* __restrict__ mbits, const bf16x8* __restrict__ Bf,
    bf16x8* __restrict__ Afrag, int Kt, int Nt) {
    __shared__ unsigned short otA[32][136];  // 272B row stride: 16B-aligned
    int t = threadIdx.x, lane = t & 63, w = t >> 6;
    int quad = lane >> 4, c16 = lane & 15;
    int wm = w & 1, wn = w >> 1;
    int mt = blockIdx.y * 2 + wm;
    int nt0 = blockIdx.x * 8 + wn * 4;
    int row = mt * 16 + (lane & 15), q8 = (lane >> 4) * 8;
    f32x4 acc[4];
#pragma unroll
    for (int j = 0; j < 4; j++) acc[j] = (f32x4){0.f, 0.f, 0.f, 0.f};
    const bf16x8* bp = Bf + (size_t)nt0 * 64 + lane;
#pragma unroll 2
    for (int kt = 0; kt < Kt; kt++) {
        unsigned int w0 = mbits[(size_t)row * 128 + kt];
        unsigned int mb0 = (w0 >> q8) & 0xffu;
        union { unsigned int u[4]; bf16x8 v; } A0;
#pragma unroll
        for (int jp = 0; jp < 4; jp++) {
            unsigned int u0 = (mb0 >> (2 * jp)) & 3u;
            A0.u[jp] = ((u0 * 0x8001u) & 0x10001u) * 0x3F80u;  // bf16 1.0 pair
        }
        bf16x8 b0 = bp[(size_t)kt * Nt * 64];
        bf16x8 b1 = bp[((size_t)kt * Nt + 1) * 64];
        bf16x8 b2 = bp[((size_t)kt * Nt + 2) * 64];
        bf16x8 b3 = bp[((size_t)kt * Nt + 3) * 64];
        acc[0] = __builtin_amdgcn_mfma_f32_16x16x32_bf16(A0.v, b0, acc[0], 0, 0, 0);
        acc[1] = __builtin_amdgcn_mfma_f32_16x16x32_bf16(A0.v, b1, acc[1], 0, 0, 0);
        acc[2] = __builtin_amdgcn_mfma_f32_16x16x32_bf16(A0.v, b2, acc[2], 0, 0, 0);
        acc[3] = __builtin_amdgcn_mfma_f32_16x16x32_bf16(A0.v, b3, acc[3], 0, 0, 0);
    }
    // transpose epilogue: C/D layout -> row-major bf16 tile in LDS -> A-frags
#pragma unroll
    for (int j = 0; j < 4; j++)
#pragma unroll
        for (int reg = 0; reg < 4; reg++)
            otA[wm * 16 + quad * 4 + reg][(wn * 4 + j) * 16 + c16] = (unsigned short)f2bf(acc[j][reg]);
    __syncthreads();
#pragma unroll
    for (int q = 0; q < 2; q++) {
        int idx = t + q * 256;             // 0..511: 2 mt x 4 kt x 64 lanes
        int mtl = idx >> 8, ktl = (idx >> 6) & 3, lane2 = idx & 63;
        int r2 = mtl * 16 + (lane2 & 15), colb = ktl * 32 + (lane2 >> 4) * 8;
        bf16x8 v = *(bf16x8*)&otA[r2][colb];
        Afrag[((size_t)(blockIdx.y * 2 + mtl) * 16 + (blockIdx.x * 4 + ktl)) * 64 + lane2] = v;
    }
}

// ---- prep: h -> HB16 (32x32x16 f16 B-frag) + srcT/dstT (log2e) + maxdst ----
__global__ __launch_bounds__(256) void prep_kernel(const float* __restrict__ h,
                                                   const float* __restrict__ aw,
                                                   const float* __restrict__ ab,
                                                   h16x8* __restrict__ HB16,
                                                   float* __restrict__ srcT,
                                                   float* __restrict__ dstT,
                                                   unsigned int* __restrict__ maxd_u) {
    __shared__ __align__(16) float hs[32][264];
    __shared__ __align__(16) float awl[KK * 512];
    int t = threadIdx.x, jb = blockIdx.x;
#pragma unroll
    for (int q = 0; q < 4; q++)
        *(float4*)&awl[(t + q * 256) * 4] = *(const float4*)&aw[(t + q * 256) * 4];
    {
        int r = t >> 3, cb = (t & 7) * 32;
        const float* hp = &h[(size_t)(jb * 32 + r) * HH + cb];
#pragma unroll
        for (int q = 0; q < 8; q++) *(float4*)&hs[r][cb + q * 4] = *(const float4*)&hp[q * 4];
    }
    __syncthreads();
#pragma unroll
    for (int it = 0; it < 4; it++) {
        int id = t + it * 256;
        int q = id >> 9, nt = (id >> 6) & 7, lane = id & 63;
        int c = nt * 32 + (lane & 31), j8 = q * 16 + (lane >> 5) * 8;
        union { unsigned int u[4]; h16x8 v; } pk;
#pragma unroll
        for (int jp = 0; jp < 4; jp++)
            pk.u[jp] = pkh(hs[j8 + 2 * jp][c], hs[j8 + 2 * jp + 1][c]);
        HB16[((size_t)(jb * 2 + q)) * 512 + nt * 64 + lane] = pk.v;
    }
    {
        const float LOG2E = 1.4426950408889634f;
        int row = t & 31, head = t >> 5;
        float s = ab[head], d = 0.f;
        const float* ws = &awl[head * 512];
        const float* wd = ws + 256;
#pragma unroll 4
        for (int c = 0; c < 256; c += 4) {
            float4 hv = *(const float4*)&hs[row][c];
            float4 a4 = *(const float4*)&ws[c];
            float4 b4 = *(const float4*)&wd[c];
            s += hv.x * a4.x + hv.y * a4.y + hv.z * a4.z + hv.w * a4.w;
            d += hv.x * b4.x + hv.y * b4.y + hv.z * b4.z + hv.w * b4.w;
        }
        float ds = d * LOG2E;
        srcT[head * NN + jb * 32 + row] = s * LOG2E;
        dstT[head * NN + jb * 32 + row] = ds;
        float mx = ds;
#pragma unroll
        for (int off = 16; off > 0; off >>= 1) mx = fmaxf(mx, __shfl_xor(mx, off));
        if (row == 0) atomicMax(&maxd_u[head], enc_f(mx));
    }
}

// ---- attention (R13 K-loop): 32 rows x 2 heads, 4 waves = jh2 x ch2 --------
// MODE 1: writes h1n A-fragments directly (LDS transpose epilogue).
// MODE 2: writes bf16 head planes row-major.
template <int MODE>
__global__ __launch_bounds__(256, 2) void attn32_kernel(
    const float* __restrict__ h, const float* __restrict__ srcT,
    const float* __restrict__ dstT, const unsigned int* __restrict__ maxd_u,
    const unsigned int* __restrict__ mbits, const h16x8* __restrict__ HB16,
    void* __restrict__ outp) {
    __shared__ __align__(16) char smraw[49664];
    __shared__ float l_all[2][2][32];
    __shared__ float linv_l[2][32];
    unsigned short* e1t = (unsigned short*)smraw;            // [2][4096] f16 (loop)
    unsigned short* e2t = (unsigned short*)(smraw + 16384);  // [2][4096] f16 (loop)
    unsigned int* mrow = (unsigned int*)(smraw + 32768);     // [32*131]      (loop)
    float* accbuf = (float*)smraw;                           // 32 KB         (epi)
    unsigned short* ot = (unsigned short*)(smraw + 32768);   // [32][264] bf16 (epi, MODE1)

    int t = threadIdx.x;
    int i0 = blockIdx.x * 32;
    int k0 = blockIdx.y * 2;

    float Dv0 = dec_f(maxd_u[k0]), Dv1 = dec_f(maxd_u[k0 + 1]);
#pragma unroll
    for (int q = 0; q < 8; q++) {
        int idx = t + q * 256;                // 0..2047, 4 entries each
        int hh = idx >> 10, off = (idx & 1023) * 4;
        float D = hh ? Dv1 : Dv0;
        float4 dv = *(const float4*)&dstT[(size_t)(k0 + hh) * NN + off];
        float d0 = dv.x - D, d1 = dv.y - D, d2 = dv.z - D, d3 = dv.w - D;
        uint2 p1, p2;
        p1.x = pkh(__builtin_amdgcn_exp2f(d0), __builtin_amdgcn_exp2f(d1));
        p1.y = pkh(__builtin_amdgcn_exp2f(d2), __builtin_amdgcn_exp2f(d3));
        p2.x = pkh(__builtin_amdgcn_exp2f(0.01f * d0), __builtin_amdgcn_exp2f(0.01f * d1));
        p2.y = pkh(__builtin_amdgcn_exp2f(0.01f * d2), __builtin_amdgcn_exp2f(0.01f * d3));
        *(uint2*)&e1t[hh * 4096 + off] = p1;
        *(uint2*)&e2t[hh * 4096 + off] = p2;
    }
#pragma unroll
    for (int q = 0; q < 16; q++) {
        int idx = t + q * 256;                // 0..4095
        int r = idx >> 7, wd = idx & 127;
        mrow[r * 131 + wd] = mbits[(size_t)(i0 + r) * 128 + wd];
    }
    __syncthreads();

    int lane = t & 63, w = t >> 6;
    int jh = w & 1, ch = w >> 1;
    int rowl = lane & 31, jsub = (lane >> 5) * 8;

    unsigned int AcPk[2], BcPk[2];
    float lacc[2] = {0.f, 0.f};
#pragma unroll
    for (int hh = 0; hh < 2; hh++) {
        float sL = srcT[(size_t)(k0 + hh) * NN + i0 + rowl];
        float xm = sL + (hh ? Dv1 : Dv0);
        float mL = fmaxf(xm, 0.01f * xm);
        float Acf = __builtin_amdgcn_exp2f(xm - mL);
        float Bcf = __builtin_amdgcn_exp2f(fmaf(0.01f, xm, -mL));
        AcPk[hh] = pkh(Acf, Acf);
        BcPk[hh] = pkh(Bcf, Bcf);
    }

    f32x16 acc[2][4];
#pragma unroll
    for (int hh = 0; hh < 2; hh++)
#pragma unroll
        for (int nt = 0; nt < 4; nt++)
#pragma unroll
            for (int r = 0; r < 16; r++) acc[hh][nt][r] = 0.f;

    const unsigned short* e1b0 = e1t;
    const unsigned short* e1b1 = e1t + 4096;
    const unsigned short* e2b0 = e2t;
    const unsigned short* e2b1 = e2t + 4096;

    int jbase = jh * 128;  // this wave's j16 range
    const h16x8* bpbase = HB16 + (size_t)(ch * 4) * 64 + lane;
    h16x8 bv0, bv1, bv2, bv3;
    {
        const h16x8* bp = bpbase + (size_t)jbase * 512;
        bv0 = bp[0]; bv1 = bp[64]; bv2 = bp[128]; bv3 = bp[192];
    }

#pragma unroll 2
    for (int it = 0; it < 128; it++) {
        int j16 = jbase + it;
        h16x8 nb0, nb1, nb2, nb3;
        {
            const h16x8* bp = bpbase + (size_t)(j16 + 1) * 512;
            nb0 = bp[0]; nb1 = bp[64]; nb2 = bp[128]; nb3 = bp[192];
        }
        unsigned int word = mrow[rowl * 131 + (j16 >> 1)];
        unsigned int mb = (word >> ((j16 & 1) * 16 + jsub)) & 0xffu;
        unsigned int mw[4];
#pragma unroll
        for (int jp = 0; jp < 4; jp++) {
            unsigned int u2 = (mb >> (2 * jp)) & 3u;
            mw[jp] = ((u2 * 0x8001u) & 0x10001u) * 0xffffu;
        }
        int eoff = j16 * 16 + jsub;
        union { unsigned int u[4]; h16x8 v; } P0;
        {
            uint4 E1 = *(const uint4*)&e1b0[eoff];
            uint4 E2 = *(const uint4*)&e2b0[eoff];
            unsigned int v0 = h2max(h2mul(E1.x, AcPk[0]), h2mul(E2.x, BcPk[0])) & mw[0];
            unsigned int v1 = h2max(h2mul(E1.y, AcPk[0]), h2mul(E2.y, BcPk[0])) & mw[1];
            unsigned int v2 = h2max(h2mul(E1.z, AcPk[0]), h2mul(E2.z, BcPk[0])) & mw[2];
            unsigned int v3 = h2max(h2mul(E1.w, AcPk[0]), h2mul(E2.w, BcPk[0])) & mw[3];
            lacc[0] = h2dot1(v0, lacc[0]);
            lacc[0] = h2dot1(v1, lacc[0]);
            lacc[0] = h2dot1(v2, lacc[0]);
            lacc[0] = h2dot1(v3, lacc[0]);
            P0.u[0] = v0; P0.u[1] = v1; P0.u[2] = v2; P0.u[3] = v3;
        }
        acc[0][0] = __builtin_amdgcn_mfma_f32_32x32x16_f16(P0.v, bv0, acc[0][0], 0, 0, 0);
        acc[0][1] = __builtin_amdgcn_mfma_f32_32x32x16_f16(P0.v, bv1, acc[0][1], 0, 0, 0);
        acc[0][2] = __builtin_amdgcn_mfma_f32_32x32x16_f16(P0.v, bv2, acc[0][2], 0, 0, 0);
        acc[0][3] = __builtin_amdgcn_mfma_f32_32x32x16_f16(P0.v, bv3, acc[0][3], 0, 0, 0);
        union { unsigned int u[4]; h16x8 v; } P1;
        {
            uint4 E1 = *(const uint4*)&e1b1[eoff];
            uint4 E2 = *(const uint4*)&e2b1[eoff];
            unsigned int v0 = h2max(h2mul(E1.x, AcPk[1]), h2mul(E2.x, BcPk[1])) & mw[0];
            unsigned int v1 = h2max(h2mul(E1.y, AcPk[1]), h2mul(E2.y, BcPk[1])) & mw[1];
            unsigned int v2 = h2max(h2mul(E1.z, AcPk[1]), h2mul(E2.z, BcPk[1])) & mw[2];
            unsigned int v3 = h2max(h2mul(E1.w, AcPk[1]), h2mul(E2.w, BcPk[1])) & mw[3];
            lacc[1] = h2dot1(v0, lacc[1]);
            lacc[1] = h2dot1(v1, lacc[1]);
            lacc[1] = h2dot1(v2, lacc[1]);
            lacc[1] = h2dot1(v3, lacc[1]);
            P1.u[0] = v0; P1.u[1] = v1; P1.u[2] = v2; P1.u[3] = v3;
        }
        acc[1][0] = __builtin_amdgcn_mfma_f32_32x32x16_f16(P1.v, bv0, acc[1][0], 0, 0, 0);
        acc[1][1] = __builtin_amdgcn_mfma_f32_32x32x16_f16(P1.v, bv1, acc[1][1], 0, 0, 0);
        acc[1][2] = __builtin_amdgcn_mfma_f32_32x32x16_f16(P1.v, bv2, acc[1][2], 0, 0, 0);
        acc[1][3] = __builtin_amdgcn_mfma_f32_32x32x16_f16(P1.v, bv3, acc[1][3], 0, 0, 0);
        bv0 = nb0; bv1 = nb1; bv2 = nb2; bv3 = nb3;
    }

    lacc[0] += __shfl_xor(lacc[0], 32);
    lacc[1] += __shfl_xor(lacc[1], 32);
    if (ch == 0 && lane < 32) {
        l_all[jh][0][lane] = lacc[0];
        l_all[jh][1][lane] = lacc[1];
    }
    __syncthreads();  // l_all visible; loop-phase LDS dead
    if (t < 32) {
#pragma unroll
        for (int hh = 0; hh < 2; hh++) {
            float lt = l_all[0][hh][t] + l_all[1][hh][t];
            linv_l[hh][t] = (lt > 0.f) ? 1.f / lt : 0.f;  // isolated row -> 0
        }
    }
    __syncthreads();

#pragma unroll
    for (int r = 0; r < 2; r++) {
        int khead = k0 + r;
        if (jh == 1) {
#pragma unroll
            for (int nt = 0; nt < 4; nt++) {
                float* dp = accbuf + (size_t)((ch * 4 + nt) * 16) * 64 + lane;
#pragma unroll
                for (int reg = 0; reg < 16; reg++) dp[reg * 64] = acc[r][nt][reg];
            }
        }
        __syncthreads();
        if (MODE == 1) {
            if (jh == 0) {
#pragma unroll
                for (int nt = 0; nt < 4; nt++) {
                    const float* sp = accbuf + (size_t)((ch * 4 + nt) * 16) * 64 + lane;
                    int c = (ch * 4 + nt) * 32 + (lane & 31);
#pragma unroll
                    for (int reg = 0; reg < 16; reg++) {
                        int rowloc = (reg & 3) + 8 * (reg >> 2) + 4 * (lane >> 5);
                        float v = (acc[r][nt][reg] + sp[reg * 64]) * linv_l[r][rowloc];
                        v += h[(size_t)(i0 + rowloc) * HH + c];
                        v = (v > 0.f) ? v : (__expf(v) - 1.f);  // elu
                        ot[rowloc * 264 + c] = (unsigned short)f2bf(v);
                    }
                }
            }
            __syncthreads();
            // all threads: write A-frags for this head (2 mt x 8 kt x 64 lanes)
            bf16x8* dstf = (bf16x8*)outp;
#pragma unroll
            for (int q = 0; q < 4; q++) {
                int idx = t + q * 256;         // 0..1023
                int mtl = idx >> 9, ktl = (idx >> 6) & 7, lane2 = idx & 63;
                int r2 = mtl * 16 + (lane2 & 15), colb = ktl * 32 + (lane2 >> 4) * 8;
                bf16x8 v = *(bf16x8*)&ot[r2 * 264 + colb];
                dstf[((size_t)(blockIdx.x * 2 + mtl) * 64 + (khead * 8 + ktl)) * 64 + lane2] = v;
            }
            if (r == 0) __syncthreads();
        } else {
            if (jh == 0) {
#pragma unroll
                for (int nt = 0; nt < 4; nt++) {
                    const float* sp = accbuf + (size_t)((ch * 4 + nt) * 16) * 64 + lane;
                    int c = (ch * 4 + nt) * 32 + (lane & 31);
#pragma unroll
                    for (int reg = 0; reg < 16; reg++) {
                        int rowloc = (reg & 3) + 8 * (reg >> 2) + 4 * (lane >> 5);
                        float v = (acc[r][nt][reg] + sp[reg * 64]) * linv_l[r][rowloc];
                        ((short*)outp)[(size_t)khead * NN * HH + (size_t)(i0 + rowloc) * HH + c] = f2bf(v);
                    }
                }
            }
            if (r == 0) __syncthreads();
        }
    }
}

// ---------------- elu(avg of heads) column partial sums (bf16 planes) --------
__global__ void colsum_kernel(const float* __restrict__ h2,
                              const short* __restrict__ heads,
                              float* __restrict__ partial) {
    int c = threadIdx.x;
    int b = blockIdx.x;
    float s = 0.f;
    for (int il = 0; il < 16; il++) {
        int i = b * 16 + il;
        float v = h2[(size_t)i * HH + c];
#pragma unroll
        for (int k = 0; k < KK; k++) {
            unsigned int bits = (unsigned int)(unsigned short)heads[(size_t)k * NN * HH + (size_t)i * HH + c];
            v += 0.125f * __uint_as_float(bits << 16);
        }
        s += (v > 0.f) ? v : (__expf(v) - 1.f);
    }
    partial[b * HH + c] = s;
}

__global__ void final_kernel(const float* __restrict__ partial,
                             const float* __restrict__ out_w,
                             const float* __restrict__ out_b,
                             float* __restrict__ dout) {
    __shared__ float red[256];
    int c = threadIdx.x;
    float s = 0.f;
    for (int b = 0; b < 256; b++) s += partial[b * HH + c];
    red[c] = (s / 4096.f) * out_w[c];
    __syncthreads();
    for (int off = 128; off > 0; off >>= 1) {
        if (c < off) red[c] += red[c + off];
        __syncthreads();
    }
    if (c == 0) dout[0] = red[0] + out_b[0];
}

extern "C" void kernel_launch(void* const* d_in, const int* in_sizes, int n_in,
                              void* d_out, int out_size, void* d_ws, size_t ws_size,
                              hipStream_t stream) {
    (void)in_sizes; (void)n_in; (void)out_size; (void)ws_size;
    const float* adj   = (const float*)d_in[0];
    const float* feats = (const float*)d_in[1];
    const float* W1_w  = (const float*)d_in[2];
    const float* W1_b  = (const float*)d_in[3];
    const float* a1_w  = (const float*)d_in[4];
    const float* a1_b  = (const float*)d_in[5];
    const float* W2_w  = (const float*)d_in[6];
    const float* W2_b  = (const float*)d_in[7];
    const float* a2_w  = (const float*)d_in[8];
    const float* a2_b  = (const float*)d_in[9];
    const float* out_w = (const float*)d_in[10];
    const float* out_b = (const float*)d_in[11];

    char* w = (char*)d_ws;
    const size_t MB = 1ull << 20;
    const size_t KB = 1ull << 10;
    // Disjoint-lifetime map (46 MB):
    unsigned int* mbits = (unsigned int*)(w);              // 0..2MB    (whole run)
    bf16x8* Bfeats = (bf16x8*)(w + 2 * MB);                // 2..6MB    (ph1)
    bf16x8* tmp1a  = (bf16x8*)(w + 14 * MB);               // 14..18MB  (ph1)
    short*  planes = (short*)(w + 2 * MB);                 // 2..18MB   (ph3)
    bf16x8* h1na   = (bf16x8*)(w + 18 * MB);               // 18..34MB  (ph2)
    float*  h2     = (float*)(w + 34 * MB);                // 34..38MB  (ph2->3)
    float*  h1     = (float*)(w + 38 * MB);                // 38..42MB  (ph1->2)
    h16x8*  HB16   = (h16x8*)(w + 42 * MB);                // 42..44MB  (ph2, ph3)
    bf16x8* W1f    = (bf16x8*)(w + 44 * MB);               // 44..44.25MB (ph1)
    bf16x8* W2f    = (bf16x8*)(w + 44 * MB + 256 * KB);    // 44.25..45.25MB (ph1->2)
    float*  srcT   = (float*)(w + 45 * MB + 256 * KB);     // 128 KB
    float*  dstT   = (float*)(w + 45 * MB + 384 * KB);     // 128 KB
    unsigned int* maxd_u = (unsigned int*)(w + 45 * MB + 512 * KB);  // 64 B (16 slots)
    float*  partial = (float*)(w + 45 * MB + 768 * KB);    // 256 KB -> ends 46MB

    // --- phase 1: h1 = (A @ feats) @ W1^T + b1 ---
    pack_mask_kernel<<<NN, 256, 0, stream>>>(adj, mbits, maxd_u);
    cvt_b_frag_kernel<FF><<<NN / 32, 256, 0, stream>>>(feats, Bfeats);
    cvt_bt2_kernel<<<dim3(HH / 16, 2), 256, 0, stream>>>(W1_w, W2_w, W1f, W2f);
    gemm_adj_kernel<<<dim3(FF / 128, NN / 32), 256, 0, stream>>>(
        mbits, Bfeats, tmp1a, NN / 32, FF / 16);
    gemm_frag_kernel<<<dim3(HH / 64, NN / 64), 256, 0, stream>>>(
        tmp1a, W1f, W1_b, h1, FF / 32, HH / 16, HH);

    // --- phase 2: layer-1 attention -> h1na (A-frag, direct), then h2 ---
    prep_kernel<<<NN / 32, 256, 0, stream>>>(h1, a1_w, a1_b, HB16, srcT, dstT, maxd_u);
    attn32_kernel<1><<<dim3(NN / 32, KK / 2), 256, 0, stream>>>(
        h1, srcT, dstT, maxd_u, mbits, HB16, h1na);
    gemm_frag_kernel<<<dim3(HH / 64, NN / 64), 256, 0, stream>>>(
        h1na, W2f, W2_b, h2, KH / 32, HH / 16, HH);

    // --- phase 3: layer-2 attention -> bf16 head planes, reduce ---
    prep_kernel<<<NN / 32, 256, 0, stream>>>(h2, a2_w, a2_b, HB16, srcT, dstT, maxd_u + 8);
    attn32_kernel<2><<<dim3(NN / 32, KK / 2), 256, 0, stream>>>(
        h2, srcT, dstT, maxd_u + 8, mbits, HB16, planes);
    colsum_kernel<<<256, 256, 0, stream>>>(h2, planes, partial);
    final_kernel<<<1, 256, 0, stream>>>(partial, out_w, out_b, (float*)d_out);
}